// Round 1
// baseline (543.953 us; speedup 1.0000x reference)
//
#include <hip/hip_runtime.h>

#define MULW 128
#define INV_S3 0.57735026918962576f
#define APITCH 136   // bf16 elements per A_lds row (pad 128 -> 136: 2-way bank aliasing, free)
#define PPITCH 68    // floats per P_lds row (pad 64 -> 68)

typedef __bf16 bf16x8 __attribute__((ext_vector_type(8)));
typedef float f32x4 __attribute__((ext_vector_type(4)));

// Pre-swizzle weights into MFMA B-fragment order, bf16.
// Bsw layout: [m(2)][ct(16)][ki(4)][lane(64)][j(8)]  (j contiguous, 16B per lane)
// m=0: [W000 | W011], m=1: [W110 | W101]
// B-frag element j of lane l for (ct,ki): B[ki*32 + (l>>4)*8 + j][ct*16 + (l&15)]
__global__ void swizzle_weights(const float* __restrict__ W000,
                                const float* __restrict__ W011,
                                const float* __restrict__ W101,
                                const float* __restrict__ W110,
                                __bf16* __restrict__ Bsw) {
    int T = blockIdx.x * blockDim.x + threadIdx.x; // 0..8191
    int m    = T >> 12;
    int ct   = (T >> 8) & 15;
    int ki   = (T >> 6) & 3;
    int lane = T & 63;
    int col = ct * 16 + (lane & 15);
    int krow0 = ki * 32 + ((lane >> 4) * 8);
    const float* src;
    int c = col;
    if (m == 0) { if (col < 128) src = W000; else { src = W011; c = col - 128; } }
    else        { if (col < 128) src = W110; else { src = W101; c = col - 128; } }
    __bf16* dst = Bsw + (size_t)T * 8;
#pragma unroll
    for (int j = 0; j < 8; ++j)
        dst[j] = (__bf16)src[(krow0 + j) * MULW + c];
}

// Per block: 32 rows of n. M-rows in LDS: 0..31 = x0[n], 32+32k+r = x1[n,:,k].
// GEMM: P[mrow][c] = sum_u A[mrow][u] * B[u][c], K=128, 256 cols.
// wave 0 -> mrows 0..31 with B0=[W000|W011]; waves 1..3 -> k=0..2 with B1=[W110|W101].
__global__ __launch_bounds__(256) void o3tp_kernel(
    const float* __restrict__ x, const float* __restrict__ y,
    const __bf16* __restrict__ Bsw, const float* __restrict__ bias,
    float* __restrict__ out, int N)
{
    __shared__ __align__(16) char smem_raw[128 * APITCH * 2]; // 34816 B, A (bf16) then reused as P (f32)
    __shared__ float ylds[32 * 4];
    __bf16* A = (__bf16*)smem_raw;
    float*  P = (float*)smem_raw;

    const int tid = threadIdx.x;
    const int n0 = blockIdx.x * 32;

    // ---- stage y ----
    if (tid < 128) {
        int r = tid >> 2, c = tid & 3;
        int n = n0 + r;
        ylds[tid] = (n < N) ? y[(size_t)n * 4 + c] : 0.f;
    }

    // ---- stage A: 32 rows x 512 f32 -> de-interleaved bf16 in LDS ----
    for (int it = 0; it < 16; ++it) {
        int F = tid + it * 256;      // float4 index, 0..4095
        int r = F >> 7;              // 0..31
        int j4 = F & 127;
        int n = n0 + r;
        float4 v = make_float4(0.f, 0.f, 0.f, 0.f);
        if (n < N) v = *(const float4*)(x + (size_t)n * 512 + j4 * 4);
        float vv[4] = {v.x, v.y, v.z, v.w};
#pragma unroll
        for (int e = 0; e < 4; ++e) {
            int j = j4 * 4 + e;
            int mrow, kk;
            if (j < 128) { mrow = r; kk = j; }
            else { int q = j - 128; int u = q / 3; int k = q - u * 3; mrow = 32 + k * 32 + r; kk = u; }
            A[mrow * APITCH + kk] = (__bf16)vv[e];
        }
    }
    __syncthreads();

    // ---- GEMM ----
    const int wv = tid >> 6;
    const int lane = tid & 63;
    const int lm = lane & 15;
    const int lq = lane >> 4;
    const int msel = (wv == 0) ? 0 : 1;

    f32x4 acc[2][16];
#pragma unroll
    for (int t = 0; t < 2; ++t)
#pragma unroll
        for (int ct = 0; ct < 16; ++ct)
            acc[t][ct] = (f32x4){0.f, 0.f, 0.f, 0.f};

    const __bf16* Bbase = Bsw + (size_t)msel * 4096 * 8;
#pragma unroll
    for (int ki = 0; ki < 4; ++ki) {
        bf16x8 afrag[2];
#pragma unroll
        for (int t = 0; t < 2; ++t) {
            int mrow = (wv * 2 + t) * 16 + lm;
            afrag[t] = *(const bf16x8*)(A + mrow * APITCH + ki * 32 + lq * 8);
        }
#pragma unroll
        for (int ct = 0; ct < 16; ++ct) {
            bf16x8 bfrag = *(const bf16x8*)(Bbase + (size_t)((ct * 4 + ki) * 64 + lane) * 8);
            acc[0][ct] = __builtin_amdgcn_mfma_f32_16x16x32_bf16(afrag[0], bfrag, acc[0][ct], 0, 0, 0);
            acc[1][ct] = __builtin_amdgcn_mfma_f32_16x16x32_bf16(afrag[1], bfrag, acc[1][ct], 0, 0, 0);
        }
    }

    // ---- epilogue: 4 chunks of 64 P-cols through LDS ----
#pragma unroll
    for (int ch = 0; ch < 4; ++ch) {
        __syncthreads();  // A reads / previous chunk reads complete
        // write P chunk (C-layout: row = quad*4+i, col = lane&15)
#pragma unroll
        for (int t = 0; t < 2; ++t) {
            int mbase = (wv * 2 + t) * 16 + lq * 4;
#pragma unroll
            for (int c4 = 0; c4 < 4; ++c4) {
                int ct = ch * 4 + c4;
                int cl = c4 * 16 + lm;  // local col within chunk
#pragma unroll
                for (int i = 0; i < 4; ++i)
                    P[(mbase + i) * PPITCH + cl] = acc[t][ct][i];
            }
        }
        __syncthreads();

        if (ch < 2) {
            // o0 cols C0..C0+63: out[n][c] = y0*P0 + inv_s3*sum_k y1k*Pk + b[c]
            int C0 = ch * 64;
#pragma unroll
            for (int p = 0; p < 2; ++p) {
                int F = tid + p * 256;   // 0..511 = 32 rows x 16 float4
                int r = F >> 4, g = F & 15;
                int n = n0 + r;
                if (n < N) {
                    const float* Pr = P + r * PPITCH + g * 4;
                    float4 p0 = *(const float4*)(Pr);
                    float4 p1 = *(const float4*)(Pr + 32 * PPITCH);
                    float4 p2 = *(const float4*)(Pr + 64 * PPITCH);
                    float4 p3 = *(const float4*)(Pr + 96 * PPITCH);
                    float4 bb = *(const float4*)(bias + C0 + g * 4);
                    float y0 = ylds[r * 4 + 0], ya = ylds[r * 4 + 1];
                    float yb = ylds[r * 4 + 2], yc = ylds[r * 4 + 3];
                    float4 o;
                    o.x = y0 * p0.x + INV_S3 * (ya * p1.x + yb * p2.x + yc * p3.x) + bb.x;
                    o.y = y0 * p0.y + INV_S3 * (ya * p1.y + yb * p2.y + yc * p3.y) + bb.y;
                    o.z = y0 * p0.z + INV_S3 * (ya * p1.z + yb * p2.z + yc * p3.z) + bb.z;
                    o.w = y0 * p0.w + INV_S3 * (ya * p1.w + yb * p2.w + yc * p3.w) + bb.w;
                    *(float4*)(out + (size_t)n * 512 + C0 + g * 4) = o;
                }
            }
        } else {
            // o1: out[n][128+3w+k] = inv_s3*(y1k*P0[128+w] + y0*Pk[128+w])
            int jbase = (ch == 2) ? 128 : 320;  // output col of first float
            int Cl0   = (ch == 2) ? 0 : 64;     // P local col = w'' - Cl0
#pragma unroll
            for (int p = 0; p < 6; ++p) {
                int F = tid + p * 256;   // 0..1535 = 32 rows x 48 float4
                int r = F / 48, g = F - 48 * (F / 48);
                int n = n0 + r;
                if (n < N) {
                    float y0 = ylds[r * 4];
                    float o[4];
#pragma unroll
                    for (int e = 0; e < 4; ++e) {
                        int j = jbase + g * 4 + e;       // global out col
                        int q = j - 128;
                        int w2 = q / 3;
                        int k = q - w2 * 3;
                        float pa = P[r * PPITCH + (w2 - Cl0)];
                        float pb = P[(32 + 32 * k + r) * PPITCH + (w2 - Cl0)];
                        o[e] = INV_S3 * (ylds[r * 4 + 1 + k] * pa + y0 * pb);
                    }
                    *(float4*)(out + (size_t)n * 512 + jbase + g * 4) = *(float4*)o;
                }
            }
        }
    }
}

extern "C" void kernel_launch(void* const* d_in, const int* in_sizes, int n_in,
                              void* d_out, int out_size, void* d_ws, size_t ws_size,
                              hipStream_t stream) {
    const float* x    = (const float*)d_in[0];
    const float* y    = (const float*)d_in[1];
    const float* W000 = (const float*)d_in[2];
    const float* W011 = (const float*)d_in[3];
    const float* W101 = (const float*)d_in[4];
    const float* W110 = (const float*)d_in[5];
    const float* bias = (const float*)d_in[6];
    float* out = (float*)d_out;
    int N = in_sizes[0] / 512;

    __bf16* Bsw = (__bf16*)d_ws;  // 2*128*256 bf16 = 128 KB
    swizzle_weights<<<32, 256, 0, stream>>>(W000, W011, W101, W110, Bsw);
    int nblk = (N + 31) / 32;
    o3tp_kernel<<<nblk, 256, 0, stream>>>(x, y, Bsw, bias, out, N);
}